// Round 11
// baseline (348.896 us; speedup 1.0000x reference)
//
#include <hip/hip_runtime.h>
#include <hip/hip_bf16.h>

#define BT_ 8192   // B*T
#define D_  512
#define V_  8192

// d_out float offsets (outputs concatenated in return order)
#define OFF_Q      0
#define OFF_TOK    4194304
#define OFF_LOSS   4202496
#define OFF_SOFT   4202497
#define OFF_LOGITS 71311361
// bf16 staging scratch at the TAIL of the soft region (soft rows >=7168):
// clobbered only by row_finish's soft writes, which run after all gemm reads.
#define STAGE_F    62922752

#define TAU  0.02f
#define EXP_NEG_TAU 0.98019867f   // exp(-0.02)
#define MAXC 64

typedef __attribute__((ext_vector_type(8))) short bf16x8;
typedef __attribute__((ext_vector_type(4))) float f32x4;
typedef __attribute__((ext_vector_type(4))) unsigned short u16x4;

__device__ __forceinline__ unsigned short bf16rne(float f) {
  unsigned int u = __float_as_uint(f);
  return (unsigned short)((u + 0x7fffu + ((u >> 16) & 1u)) >> 16);
}

// ---------------- pass 0: fp32 -> bf16 for X and W (block-uniform source) ----------------
__global__ __launch_bounds__(256) void to_bf16_k(const f32x4* __restrict__ x,
                                                 const f32x4* __restrict__ w,
                                                 u16x4* __restrict__ xa,
                                                 u16x4* __restrict__ wb) {
  const int n4 = (BT_ * D_) / 4;
  const int half = gridDim.x >> 1;
  const bool isw = blockIdx.x >= half;
  const f32x4* __restrict__ s = isw ? w : x;
  u16x4* __restrict__ d = isw ? wb : xa;
  const int b0 = isw ? blockIdx.x - half : blockIdx.x;
  for (int i = b0 * 256 + threadIdx.x; i < n4; i += half * 256) {
    const f32x4 v = s[i];
    u16x4 o;
    o[0] = bf16rne(v[0]); o[1] = bf16rne(v[1]);
    o[2] = bf16rne(v[2]); o[3] = bf16rne(v[3]);
    d[i] = o;
  }
}

// ---------------- pass 1: 256x256 8-phase bf16 MFMA GEMM (pure-store epilogue) ----------------
__device__ __forceinline__ void gload_lds16(const void* g, void* l) {
  __builtin_amdgcn_global_load_lds((const __attribute__((address_space(1))) void*)g,
                                   (__attribute__((address_space(3))) void*)l,
                                   16, 0, 0);
}

__device__ __forceinline__ void barf() {
  __builtin_amdgcn_s_barrier();
  asm volatile("" ::: "memory");
}
__device__ __forceinline__ void vmcnt2() { asm volatile("s_waitcnt vmcnt(2)" ::: "memory"); }
__device__ __forceinline__ void vmcnt0() { asm volatile("s_waitcnt vmcnt(0)" ::: "memory"); }

// stage one half-tile (16 KB) of K-tile `ktile`; LDS dest linear, global source
// inverse-swizzled (T2 both-sides): addr ^= ((row&7)<<4).
__device__ __forceinline__ void stage_unit(const char* __restrict__ tb, char* ldsRegion,
                                           int ktile, int half, int wid, int lane) {
#pragma unroll
  for (int issue = 0; issue < 2; ++issue) {
    const int d = half * 16384 + issue * 8192 + wid * 1024 + lane * 16;
    const int l = d ^ (((d >> 7) & 7) << 4);
    gload_lds16(tb + (size_t)(l >> 7) * 1024 + ktile * 128 + (l & 127),
                ldsRegion + half * 16384 + issue * 8192 + wid * 1024);
  }
}

__device__ __forceinline__ bf16x8 rdfrag(const char* base, int R, int ks, int g) {
  return *(const bf16x8*)(base + R * 128 + ((ks * 64 + 16 * g) ^ ((R & 7) << 4)));
}

__device__ __forceinline__ void kgroup(int t, int smode, char* lds,
                                       const char* __restrict__ Ab,
                                       const char* __restrict__ Bb,
                                       int wr, int wc, int lane, int wid,
                                       f32x4 (&acc)[8][4]) {
  char* aL = lds + (t & 1) * 32768;
  char* bL = lds + 65536 + (t & 1) * 32768;
  char* aS = lds + ((t & 1) ^ 1) * 32768;
  char* bS = lds + 65536 + ((t & 1) ^ 1) * 32768;
  const int cg = lane & 15, g = lane >> 4;
  bf16x8 a[4][2], b0[2][2], b1[2][2];

  // ---- phase 1: read A01 + B01 of t; stage (t+1).A-half1
#pragma unroll
  for (int m = 0; m < 4; ++m)
#pragma unroll
    for (int ks = 0; ks < 2; ++ks)
      a[m][ks] = rdfrag(aL, wr * 128 + m * 16 + cg, ks, g);
#pragma unroll
  for (int n = 0; n < 2; ++n)
#pragma unroll
    for (int ks = 0; ks < 2; ++ks)
      b0[n][ks] = rdfrag(bL, wc * 64 + n * 16 + cg, ks, g);
  if (smode >= 1) stage_unit(Ab, aS, t + 1, 1, wid, lane);
  barf();
  __builtin_amdgcn_s_setprio(1);
#pragma unroll
  for (int m = 0; m < 4; ++m)
#pragma unroll
    for (int n = 0; n < 2; ++n)
#pragma unroll
      for (int ks = 0; ks < 2; ++ks)
        acc[m][n] = __builtin_amdgcn_mfma_f32_16x16x32_bf16(a[m][ks], b0[n][ks], acc[m][n], 0, 0, 0);
  __builtin_amdgcn_s_setprio(0);
  barf();

  // ---- phase 2: read B23 of t; stage (t+1).B-half0
#pragma unroll
  for (int n = 0; n < 2; ++n)
#pragma unroll
    for (int ks = 0; ks < 2; ++ks)
      b1[n][ks] = rdfrag(bL, wc * 64 + (n + 2) * 16 + cg, ks, g);
  if (smode >= 1) stage_unit(Bb, bS, t + 1, 0, wid, lane);
  barf();
  __builtin_amdgcn_s_setprio(1);
#pragma unroll
  for (int m = 0; m < 4; ++m)
#pragma unroll
    for (int n = 0; n < 2; ++n)
#pragma unroll
      for (int ks = 0; ks < 2; ++ks)
        acc[m][n + 2] = __builtin_amdgcn_mfma_f32_16x16x32_bf16(a[m][ks], b1[n][ks], acc[m][n + 2], 0, 0, 0);
  __builtin_amdgcn_s_setprio(0);
  barf();

  // ---- phase 3: read A23 of t; stage (t+1).B-half1
#pragma unroll
  for (int m = 0; m < 4; ++m)
#pragma unroll
    for (int ks = 0; ks < 2; ++ks)
      a[m][ks] = rdfrag(aL, wr * 128 + (m + 4) * 16 + cg, ks, g);
  if (smode >= 1) stage_unit(Bb, bS, t + 1, 1, wid, lane);
  barf();
  __builtin_amdgcn_s_setprio(1);
#pragma unroll
  for (int m = 0; m < 4; ++m)
#pragma unroll
    for (int n = 0; n < 2; ++n)
#pragma unroll
      for (int ks = 0; ks < 2; ++ks)
        acc[m + 4][n + 2] = __builtin_amdgcn_mfma_f32_16x16x32_bf16(a[m][ks], b1[n][ks], acc[m + 4][n + 2], 0, 0, 0);
  __builtin_amdgcn_s_setprio(0);
  barf();

  // ---- phase 4: MFMA A23 x B01; stage (t+2).A-half0 into read-parity buf
  if (smode == 2) stage_unit(Ab, aL, t + 2, 0, wid, lane);
  barf();
  __builtin_amdgcn_s_setprio(1);
#pragma unroll
  for (int m = 0; m < 4; ++m)
#pragma unroll
    for (int n = 0; n < 2; ++n)
#pragma unroll
      for (int ks = 0; ks < 2; ++ks)
        acc[m + 4][n] = __builtin_amdgcn_mfma_f32_16x16x32_bf16(a[m][ks], b0[n][ks], acc[m + 4][n], 0, 0, 0);
  __builtin_amdgcn_s_setprio(0);
  if (smode == 2) vmcnt2();
  else if (smode == 1) vmcnt0();
  barf();
}

__global__ __launch_bounds__(512) void gemm8(const unsigned short* __restrict__ A,
                                             const unsigned short* __restrict__ B,
                                             const float* __restrict__ bias,
                                             float* __restrict__ C) {
  __shared__ char lds[131072];  // A dbuf 64K | B dbuf 64K ; reused as C retile
  const int tid  = threadIdx.x;
  const int lane = tid & 63;
  const int wid  = tid >> 6;           // 8 waves: 2M x 4N
  const int wr   = wid >> 2, wc = wid & 3;

  // bijective XCD chunking over the 32x32 block grid (8x16 blocks per XCD)
  const int bid = blockIdx.x;
  const int xcd = bid & 7;
  const int s   = bid >> 3;
  const int by  = (xcd >> 1) * 8 + (s >> 4);
  const int bx  = (xcd & 1) * 16 + (s & 15);
  const int row0 = by * 256, col0 = bx * 256;

  const char* Ab = (const char*)A + (size_t)row0 * (D_ * 2);
  const char* Bb = (const char*)B + (size_t)col0 * (D_ * 2);

  f32x4 acc[8][4] = {};

  // prologue: stage tile0 fully + tile1.A-half0
  stage_unit(Ab, lds, 0, 0, wid, lane);
  stage_unit(Ab, lds, 0, 1, wid, lane);
  stage_unit(Bb, lds + 65536, 0, 0, wid, lane);
  stage_unit(Bb, lds + 65536, 0, 1, wid, lane);
  stage_unit(Ab, lds + 32768, 1, 0, wid, lane);
  vmcnt2();
  barf();

  for (int t = 0; t < 6; ++t)
    kgroup(t, 2, lds, Ab, Bb, wr, wc, lane, wid, acc);
  kgroup(6, 1, lds, Ab, Bb, wr, wc, lane, wid, acc);
  kgroup(7, 0, lds, Ab, Bb, wr, wc, lane, wid, acc);

  // ---- epilogue: PURE retile + coalesced 1KB row stores ----
  // LDS rows rotated by -3 cols so the (base%4==1) global misalignment maps to
  // aligned LDS f32x4 reads: lds word (c+253)&255 holds col c.
  const int cg = lane & 15, g = lane >> 4;
  float bv[4];
#pragma unroll
  for (int n = 0; n < 4; ++n) bv[n] = bias[col0 + wc * 64 + n * 16 + cg];

  float* cl = (float*)lds;
  __syncthreads();
#pragma unroll
  for (int h = 0; h < 2; ++h) {
    if (wr == h) {
#pragma unroll
      for (int m = 0; m < 8; ++m)
#pragma unroll
        for (int n = 0; n < 4; ++n) {
          const int cw = ((wc * 64 + n * 16 + cg) + 253) & 255;
#pragma unroll
          for (int rr = 0; rr < 4; ++rr) {
            const int R = m * 16 + 4 * g + rr;
            cl[R * 256 + cw] = acc[m][n][rr] + bv[n];
          }
        }
    }
    __syncthreads();
#pragma unroll
    for (int k = 0; k < 16; ++k) {
      const int r = wid * 16 + k;
      const f32x4 v = *(const f32x4*)((char*)cl + r * 1024 + lane * 16);
      const int grow = row0 + h * 128 + r;
      float* Crow = C + (size_t)grow * V_ + col0;
      if (lane < 63) {
        *((f32x4*)(Crow + 3) + lane) = v;   // plain: row_finish re-reads soon
      } else {
        Crow[255] = v[0]; Crow[0] = v[1]; Crow[1] = v[2]; Crow[2] = v[3];
      }
    }
    __syncthreads();
  }
}

// ---- pass 2 (fused): single-pass row softmax + exact-fp32 argmax rescue
//      + codebook gather (quantized) + commitment-loss contribution.
// Rows processed in REVERSE order: gemm wrote rows ascending, so the youngest
// rows are still L3-resident when we read them first (anti-LRU fix).
__global__ __launch_bounds__(256) void row_finish(const float* __restrict__ logits,
                                                  const float* __restrict__ xf,
                                                  const float* __restrict__ wf,
                                                  const float* __restrict__ bias,
                                                  const float* __restrict__ cb,
                                                  float* __restrict__ tokf,
                                                  float* __restrict__ soft,
                                                  float* __restrict__ q,
                                                  float* __restrict__ loss) {
  const int row  = (BT_ - 1) - blockIdx.x;   // reverse order
  const int tid  = threadIdx.x;
  const int lane = tid & 63;
  const int wv   = tid >> 6;

  __shared__ float redM[4], redS[4];
  __shared__ int   cnum;
  __shared__ int   cidx[MAXC];
  __shared__ int   bestiS;

  const float* L = logits + (size_t)row * V_;
  float*       S = soft   + (size_t)row * V_;
  const f32x4* L4 = (const f32x4*)(L + 3);  // 16B-aligned; valid i in [0,2047)
  f32x4*       S4 = (f32x4*)(S + 3);

  // phase A: load + exp (once), per-thread max/sum
  f32x4 e[8];
  float m_e = 0.f, s = 0.f;   // all e > 0
#pragma unroll
  for (int j = 0; j < 8; ++j) {
    const int i = j * 256 + tid;
    if (i < 2047) {
      const f32x4 v = L4[i];
      f32x4 t;
      t[0] = __expf(v[0]); t[1] = __expf(v[1]);
      t[2] = __expf(v[2]); t[3] = __expf(v[3]);
      e[j] = t;
      m_e = fmaxf(m_e, fmaxf(fmaxf(t[0], t[1]), fmaxf(t[2], t[3])));
      s += t[0] + t[1] + t[2] + t[3];
    } else {
      e[j][0] = 0.f; e[j][1] = 0.f; e[j][2] = 0.f; e[j][3] = 0.f;
    }
  }
  // head (cols 0..2) + tail (col 8191) extras on threads 0..3
  float extra_e = 0.f;
  int   extra_col = -1;
  if (tid < 3)       extra_col = tid;
  else if (tid == 3) extra_col = 8191;
  if (extra_col >= 0) {
    extra_e = __expf(L[extra_col]);
    m_e = fmaxf(m_e, extra_e);
    s += extra_e;
  }
  // block reduce
#pragma unroll
  for (int o = 1; o < 64; o <<= 1) {
    m_e = fmaxf(m_e, __shfl_xor(m_e, o));
    s += __shfl_xor(s, o);
  }
  if (lane == 0) { redM[wv] = m_e; redS[wv] = s; }
  if (tid == 0) cnum = 0;
  __syncthreads();
  m_e = fmaxf(fmaxf(redM[0], redM[1]), fmaxf(redM[2], redM[3]));
  s   = redS[0] + redS[1] + redS[2] + redS[3];
  const float si    = 1.0f / s;
  const float thr_e = m_e * EXP_NEG_TAU;   // e >= thr_e  <=>  logit >= max - TAU

  // candidate collection (monotonic in e)
#pragma unroll
  for (int j = 0; j < 8; ++j) {
    const int i = j * 256 + tid;
#pragma unroll
    for (int qq = 0; qq < 4; ++qq)
      if (e[j][qq] >= thr_e) {
        const int p = atomicAdd(&cnum, 1);
        if (p < MAXC) cidx[p] = 3 + 4 * i + qq;
      }
  }
  if (extra_col >= 0 && extra_e >= thr_e) {
    const int p = atomicAdd(&cnum, 1);
    if (p < MAXC) cidx[p] = extra_col;
  }
  __syncthreads();

  // wave 0: exact-fp32 rescue over candidates; waves 1-3 go straight to stores
  if (wv == 0) {
    const int cnt = min(cnum, MAXC);
    float bestv = -1e30f;
    int   besti = 0x7fffffff;
    const float4* xr4 = (const float4*)(xf + (size_t)row * D_);
    for (int c = 0; c < cnt; ++c) {
      const int col = cidx[c];
      const float4* wr4 = (const float4*)(wf + (size_t)col * D_);
      float p = 0.f;
#pragma unroll
      for (int qq = 0; qq < 2; ++qq) {
        const float4 av = xr4[lane + 64 * qq];
        const float4 bvv = wr4[lane + 64 * qq];
        p += av.x * bvv.x + av.y * bvv.y + av.z * bvv.z + av.w * bvv.w;
      }
#pragma unroll
      for (int o = 1; o < 64; o <<= 1) p += __shfl_xor(p, o);
      const float tot = p + bias[col];
      if (tot > bestv || (tot == bestv && col < besti)) { bestv = tot; besti = col; }
    }
    if (lane == 0) { tokf[row] = (float)besti; bestiS = besti; }
  }

  // phase B: soft = e * si from registers (nt: never re-read)
#pragma unroll
  for (int j = 0; j < 8; ++j) {
    const int i = j * 256 + tid;
    if (i < 2047) {
      f32x4 o;
      o[0] = e[j][0] * si; o[1] = e[j][1] * si;
      o[2] = e[j][2] * si; o[3] = e[j][3] * si;
      __builtin_nontemporal_store(o, S4 + i);
    }
  }
  if (extra_col >= 0) S[extra_col] = extra_e * si;

  // phase C (fused finalize): quantized gather + loss contribution
  __syncthreads();
  const int bi = bestiS;
  if (tid < 128) {   // 128 f32x4 = 512 floats (waves 0-1)
    const f32x4 cv = *((const f32x4*)(cb + (size_t)bi * D_) + tid);
    const f32x4 xv = *((const f32x4*)(xf + (size_t)row * D_) + tid);
    __builtin_nontemporal_store(cv, (f32x4*)(q + (size_t)row * D_) + tid);
    const float dx = cv[0] - xv[0], dy = cv[1] - xv[1];
    const float dz = cv[2] - xv[2], dw = cv[3] - xv[3];
    float ls = dx * dx + dy * dy + dz * dz + dw * dw;
#pragma unroll
    for (int o = 1; o < 64; o <<= 1) ls += __shfl_xor(ls, o);
    if (lane == 0) atomicAdd(loss, ls * (1.0f / 4194304.0f));
  }
}

extern "C" void kernel_launch(void* const* d_in, const int* in_sizes, int n_in,
                              void* d_out, int out_size, void* d_ws, size_t ws_size,
                              hipStream_t stream) {
  const float* x  = (const float*)d_in[0];  // inputs   [8192][512]
  const float* cb = (const float*)d_in[1];  // codebook [8192][512]
  const float* wl = (const float*)d_in[2];  // W_logits [8192][512]
  const float* bl = (const float*)d_in[3];  // b_logits [8192]
  float* out = (float*)d_out;

  float* qout   = out + OFF_Q;
  float* tokf   = out + OFF_TOK;
  float* loss   = out + OFF_LOSS;
  float* soft   = out + OFF_SOFT;
  float* logits = out + OFF_LOGITS;

  // scratch: bf16 staging at soft-region tail (rows >=7168) — read only by gemm,
  // overwritten by row_finish's soft writes which run strictly after gemm.
  unsigned short* Abf = (unsigned short*)(out + STAGE_F);
  unsigned short* Wbf = Abf + (size_t)BT_ * D_;

  hipMemsetAsync(loss, 0, 4, stream);

  to_bf16_k<<<2048, 256, 0, stream>>>((const f32x4*)x, (const f32x4*)wl,
                                      (u16x4*)Abf, (u16x4*)Wbf);
  gemm8<<<1024, 512, 0, stream>>>(Abf, Wbf, bl, logits);
  row_finish<<<8192, 256, 0, stream>>>(logits, x, wl, bl, cb, tokf, soft, qout, loss);
}

// Round 12
// 323.967 us; speedup vs baseline: 1.0769x; 1.0769x over previous
//
#include <hip/hip_runtime.h>
#include <hip/hip_bf16.h>

#define BT_ 8192   // B*T
#define D_  512
#define V_  8192

// d_out float offsets (outputs concatenated in return order)
#define OFF_Q      0
#define OFF_TOK    4194304
#define OFF_LOSS   4202496
#define OFF_SOFT   4202497
#define OFF_LOGITS 71311361
// bf16 staging scratch at the TAIL of the soft region (soft rows >=7168):
// clobbered only by row_finish's soft writes, which run after all gemm reads.
#define STAGE_F    62922752

#define TAU  0.02f
#define EXP_NEG_TAU 0.98019867f   // exp(-0.02)
#define MAXC 64

typedef __attribute__((ext_vector_type(8))) short bf16x8;
typedef __attribute__((ext_vector_type(4))) float f32x4;
typedef __attribute__((ext_vector_type(4))) unsigned short u16x4;

__device__ __forceinline__ unsigned short bf16rne(float f) {
  unsigned int u = __float_as_uint(f);
  return (unsigned short)((u + 0x7fffu + ((u >> 16) & 1u)) >> 16);
}

// ---------------- pass 0: fp32 -> bf16 for X and W (block-uniform source) ----------------
__global__ __launch_bounds__(256) void to_bf16_k(const f32x4* __restrict__ x,
                                                 const f32x4* __restrict__ w,
                                                 u16x4* __restrict__ xa,
                                                 u16x4* __restrict__ wb) {
  const int n4 = (BT_ * D_) / 4;
  const int half = gridDim.x >> 1;
  const bool isw = blockIdx.x >= half;
  const f32x4* __restrict__ s = isw ? w : x;
  u16x4* __restrict__ d = isw ? wb : xa;
  const int b0 = isw ? blockIdx.x - half : blockIdx.x;
  for (int i = b0 * 256 + threadIdx.x; i < n4; i += half * 256) {
    const f32x4 v = s[i];
    u16x4 o;
    o[0] = bf16rne(v[0]); o[1] = bf16rne(v[1]);
    o[2] = bf16rne(v[2]); o[3] = bf16rne(v[3]);
    d[i] = o;
  }
}

// ---------------- pass 1: 256x256 8-phase bf16 MFMA GEMM (pure-store epilogue) ----------------
__device__ __forceinline__ void gload_lds16(const void* g, void* l) {
  __builtin_amdgcn_global_load_lds((const __attribute__((address_space(1))) void*)g,
                                   (__attribute__((address_space(3))) void*)l,
                                   16, 0, 0);
}

__device__ __forceinline__ void barf() {
  __builtin_amdgcn_s_barrier();
  asm volatile("" ::: "memory");
}
__device__ __forceinline__ void vmcnt2() { asm volatile("s_waitcnt vmcnt(2)" ::: "memory"); }
__device__ __forceinline__ void vmcnt0() { asm volatile("s_waitcnt vmcnt(0)" ::: "memory"); }

// stage one half-tile (16 KB) of K-tile `ktile`; LDS dest linear, global source
// inverse-swizzled (T2 both-sides): addr ^= ((row&7)<<4).
__device__ __forceinline__ void stage_unit(const char* __restrict__ tb, char* ldsRegion,
                                           int ktile, int half, int wid, int lane) {
#pragma unroll
  for (int issue = 0; issue < 2; ++issue) {
    const int d = half * 16384 + issue * 8192 + wid * 1024 + lane * 16;
    const int l = d ^ (((d >> 7) & 7) << 4);
    gload_lds16(tb + (size_t)(l >> 7) * 1024 + ktile * 128 + (l & 127),
                ldsRegion + half * 16384 + issue * 8192 + wid * 1024);
  }
}

__device__ __forceinline__ bf16x8 rdfrag(const char* base, int R, int ks, int g) {
  return *(const bf16x8*)(base + R * 128 + ((ks * 64 + 16 * g) ^ ((R & 7) << 4)));
}

__device__ __forceinline__ void kgroup(int t, int smode, char* lds,
                                       const char* __restrict__ Ab,
                                       const char* __restrict__ Bb,
                                       int wr, int wc, int lane, int wid,
                                       f32x4 (&acc)[8][4]) {
  char* aL = lds + (t & 1) * 32768;
  char* bL = lds + 65536 + (t & 1) * 32768;
  char* aS = lds + ((t & 1) ^ 1) * 32768;
  char* bS = lds + 65536 + ((t & 1) ^ 1) * 32768;
  const int cg = lane & 15, g = lane >> 4;
  bf16x8 a[4][2], b0[2][2], b1[2][2];

  // ---- phase 1: read A01 + B01 of t; stage (t+1).A-half1
#pragma unroll
  for (int m = 0; m < 4; ++m)
#pragma unroll
    for (int ks = 0; ks < 2; ++ks)
      a[m][ks] = rdfrag(aL, wr * 128 + m * 16 + cg, ks, g);
#pragma unroll
  for (int n = 0; n < 2; ++n)
#pragma unroll
    for (int ks = 0; ks < 2; ++ks)
      b0[n][ks] = rdfrag(bL, wc * 64 + n * 16 + cg, ks, g);
  if (smode >= 1) stage_unit(Ab, aS, t + 1, 1, wid, lane);
  barf();
  __builtin_amdgcn_s_setprio(1);
#pragma unroll
  for (int m = 0; m < 4; ++m)
#pragma unroll
    for (int n = 0; n < 2; ++n)
#pragma unroll
      for (int ks = 0; ks < 2; ++ks)
        acc[m][n] = __builtin_amdgcn_mfma_f32_16x16x32_bf16(a[m][ks], b0[n][ks], acc[m][n], 0, 0, 0);
  __builtin_amdgcn_s_setprio(0);
  barf();

  // ---- phase 2: read B23 of t; stage (t+1).B-half0
#pragma unroll
  for (int n = 0; n < 2; ++n)
#pragma unroll
    for (int ks = 0; ks < 2; ++ks)
      b1[n][ks] = rdfrag(bL, wc * 64 + (n + 2) * 16 + cg, ks, g);
  if (smode >= 1) stage_unit(Bb, bS, t + 1, 0, wid, lane);
  barf();
  __builtin_amdgcn_s_setprio(1);
#pragma unroll
  for (int m = 0; m < 4; ++m)
#pragma unroll
    for (int n = 0; n < 2; ++n)
#pragma unroll
      for (int ks = 0; ks < 2; ++ks)
        acc[m][n + 2] = __builtin_amdgcn_mfma_f32_16x16x32_bf16(a[m][ks], b1[n][ks], acc[m][n + 2], 0, 0, 0);
  __builtin_amdgcn_s_setprio(0);
  barf();

  // ---- phase 3: read A23 of t; stage (t+1).B-half1
#pragma unroll
  for (int m = 0; m < 4; ++m)
#pragma unroll
    for (int ks = 0; ks < 2; ++ks)
      a[m][ks] = rdfrag(aL, wr * 128 + (m + 4) * 16 + cg, ks, g);
  if (smode >= 1) stage_unit(Bb, bS, t + 1, 1, wid, lane);
  barf();
  __builtin_amdgcn_s_setprio(1);
#pragma unroll
  for (int m = 0; m < 4; ++m)
#pragma unroll
    for (int n = 0; n < 2; ++n)
#pragma unroll
      for (int ks = 0; ks < 2; ++ks)
        acc[m + 4][n + 2] = __builtin_amdgcn_mfma_f32_16x16x32_bf16(a[m][ks], b1[n][ks], acc[m + 4][n + 2], 0, 0, 0);
  __builtin_amdgcn_s_setprio(0);
  barf();

  // ---- phase 4: MFMA A23 x B01; stage (t+2).A-half0 into read-parity buf
  if (smode == 2) stage_unit(Ab, aL, t + 2, 0, wid, lane);
  barf();
  __builtin_amdgcn_s_setprio(1);
#pragma unroll
  for (int m = 0; m < 4; ++m)
#pragma unroll
    for (int n = 0; n < 2; ++n)
#pragma unroll
      for (int ks = 0; ks < 2; ++ks)
        acc[m + 4][n] = __builtin_amdgcn_mfma_f32_16x16x32_bf16(a[m][ks], b0[n][ks], acc[m + 4][n], 0, 0, 0);
  __builtin_amdgcn_s_setprio(0);
  if (smode == 2) vmcnt2();
  else if (smode == 1) vmcnt0();
  barf();
}

__global__ __launch_bounds__(512) void gemm8(const unsigned short* __restrict__ A,
                                             const unsigned short* __restrict__ B,
                                             const float* __restrict__ bias,
                                             float* __restrict__ C) {
  __shared__ char lds[131072];  // A dbuf 64K | B dbuf 64K ; reused as C retile
  const int tid  = threadIdx.x;
  const int lane = tid & 63;
  const int wid  = tid >> 6;           // 8 waves: 2M x 4N
  const int wr   = wid >> 2, wc = wid & 3;

  // bijective XCD chunking over the 32x32 block grid (8x16 blocks per XCD)
  const int bid = blockIdx.x;
  const int xcd = bid & 7;
  const int s   = bid >> 3;
  const int by  = (xcd >> 1) * 8 + (s >> 4);
  const int bx  = (xcd & 1) * 16 + (s & 15);
  const int row0 = by * 256, col0 = bx * 256;

  const char* Ab = (const char*)A + (size_t)row0 * (D_ * 2);
  const char* Bb = (const char*)B + (size_t)col0 * (D_ * 2);

  f32x4 acc[8][4] = {};

  // prologue: stage tile0 fully + tile1.A-half0
  stage_unit(Ab, lds, 0, 0, wid, lane);
  stage_unit(Ab, lds, 0, 1, wid, lane);
  stage_unit(Bb, lds + 65536, 0, 0, wid, lane);
  stage_unit(Bb, lds + 65536, 0, 1, wid, lane);
  stage_unit(Ab, lds + 32768, 1, 0, wid, lane);
  vmcnt2();
  barf();

  for (int t = 0; t < 6; ++t)
    kgroup(t, 2, lds, Ab, Bb, wr, wc, lane, wid, acc);
  kgroup(6, 1, lds, Ab, Bb, wr, wc, lane, wid, acc);
  kgroup(7, 0, lds, Ab, Bb, wr, wc, lane, wid, acc);

  // ---- epilogue: PURE retile + coalesced 1KB row stores ----
  // LDS rows rotated by -3 cols so the (base%4==1) global misalignment maps to
  // aligned LDS f32x4 reads: lds word (c+253)&255 holds col c.
  const int cg = lane & 15, g = lane >> 4;
  float bv[4];
#pragma unroll
  for (int n = 0; n < 4; ++n) bv[n] = bias[col0 + wc * 64 + n * 16 + cg];

  float* cl = (float*)lds;
  __syncthreads();
#pragma unroll
  for (int h = 0; h < 2; ++h) {
    if (wr == h) {
#pragma unroll
      for (int m = 0; m < 8; ++m)
#pragma unroll
        for (int n = 0; n < 4; ++n) {
          const int cw = ((wc * 64 + n * 16 + cg) + 253) & 255;
#pragma unroll
          for (int rr = 0; rr < 4; ++rr) {
            const int R = m * 16 + 4 * g + rr;
            cl[R * 256 + cw] = acc[m][n][rr] + bv[n];
          }
        }
    }
    __syncthreads();
#pragma unroll
    for (int k = 0; k < 16; ++k) {
      const int r = wid * 16 + k;
      const f32x4 v = *(const f32x4*)((char*)cl + r * 1024 + lane * 16);
      const int grow = row0 + h * 128 + r;
      float* Crow = C + (size_t)grow * V_ + col0;
      if (lane < 63) {
        *((f32x4*)(Crow + 3) + lane) = v;   // plain: row_finish re-reads soon
      } else {
        Crow[255] = v[0]; Crow[0] = v[1]; Crow[1] = v[2]; Crow[2] = v[3];
      }
    }
    __syncthreads();
  }
}

// ---- pass 2: single-pass row softmax + exact-fp32 argmax rescue (register-resident) ----
// Row mapping = write-recency LIFO: gemm generation g wrote panels with
// (by&7) in {2g, 2g+1}; we read gen 3 first (still L3-resident), then 2,1,0 —
// consuming L3 hits before our own miss-allocations evict them.
__global__ __launch_bounds__(256) void row_finish(const float* __restrict__ logits,
                                                  const float* __restrict__ xf,
                                                  const float* __restrict__ wf,
                                                  const float* __restrict__ bias,
                                                  float* __restrict__ tokf,
                                                  float* __restrict__ soft) {
  const int b    = blockIdx.x;
  const int gen  = 3 - (b >> 11);          // newest generation first
  const int idx  = b & 2047;
  const int p    = idx >> 8;               // 0..7 panel within generation
  const int by   = (p >> 1) * 8 + gen * 2 + (p & 1);
  const int row  = by * 256 + (idx & 255);
  const int tid  = threadIdx.x;
  const int lane = tid & 63;
  const int wv   = tid >> 6;

  __shared__ float redM[4], redS[4];
  __shared__ int   cnum;
  __shared__ int   cidx[MAXC];

  const float* L = logits + (size_t)row * V_;
  float*       S = soft   + (size_t)row * V_;
  const f32x4* L4 = (const f32x4*)(L + 3);  // 16B-aligned; valid i in [0,2047)
  f32x4*       S4 = (f32x4*)(S + 3);

  // phase A: load + exp (once), per-thread max/sum
  f32x4 e[8];
  float m_e = 0.f, s = 0.f;   // all e > 0
#pragma unroll
  for (int j = 0; j < 8; ++j) {
    const int i = j * 256 + tid;
    if (i < 2047) {
      const f32x4 v = L4[i];
      f32x4 t;
      t[0] = __expf(v[0]); t[1] = __expf(v[1]);
      t[2] = __expf(v[2]); t[3] = __expf(v[3]);
      e[j] = t;
      m_e = fmaxf(m_e, fmaxf(fmaxf(t[0], t[1]), fmaxf(t[2], t[3])));
      s += t[0] + t[1] + t[2] + t[3];
    } else {
      e[j][0] = 0.f; e[j][1] = 0.f; e[j][2] = 0.f; e[j][3] = 0.f;
    }
  }
  // head (cols 0..2) + tail (col 8191) extras on threads 0..3
  float extra_e = 0.f;
  int   extra_col = -1;
  if (tid < 3)       extra_col = tid;
  else if (tid == 3) extra_col = 8191;
  if (extra_col >= 0) {
    extra_e = __expf(L[extra_col]);
    m_e = fmaxf(m_e, extra_e);
    s += extra_e;
  }
  // block reduce
#pragma unroll
  for (int o = 1; o < 64; o <<= 1) {
    m_e = fmaxf(m_e, __shfl_xor(m_e, o));
    s += __shfl_xor(s, o);
  }
  if (lane == 0) { redM[wv] = m_e; redS[wv] = s; }
  if (tid == 0) cnum = 0;
  __syncthreads();
  m_e = fmaxf(fmaxf(redM[0], redM[1]), fmaxf(redM[2], redM[3]));
  s   = redS[0] + redS[1] + redS[2] + redS[3];
  const float si    = 1.0f / s;
  const float thr_e = m_e * EXP_NEG_TAU;   // e >= thr_e  <=>  logit >= max - TAU

  // candidate collection (monotonic in e)
#pragma unroll
  for (int j = 0; j < 8; ++j) {
    const int i = j * 256 + tid;
#pragma unroll
    for (int q = 0; q < 4; ++q)
      if (e[j][q] >= thr_e) {
        const int pp = atomicAdd(&cnum, 1);
        if (pp < MAXC) cidx[pp] = 3 + 4 * i + q;
      }
  }
  if (extra_col >= 0 && extra_e >= thr_e) {
    const int pp = atomicAdd(&cnum, 1);
    if (pp < MAXC) cidx[pp] = extra_col;
  }
  __syncthreads();

  // wave 0: exact-fp32 rescue over candidates; waves 1-3 go straight to stores
  if (wv == 0) {
    const int cnt = min(cnum, MAXC);
    float bestv = -1e30f;
    int   besti = 0x7fffffff;
    const float4* xr4 = (const float4*)(xf + (size_t)row * D_);
    for (int c = 0; c < cnt; ++c) {
      const int col = cidx[c];
      const float4* wr4 = (const float4*)(wf + (size_t)col * D_);
      float pr = 0.f;
#pragma unroll
      for (int q = 0; q < 2; ++q) {
        const float4 av = xr4[lane + 64 * q];
        const float4 bvv = wr4[lane + 64 * q];
        pr += av.x * bvv.x + av.y * bvv.y + av.z * bvv.z + av.w * bvv.w;
      }
#pragma unroll
      for (int o = 1; o < 64; o <<= 1) pr += __shfl_xor(pr, o);
      const float tot = pr + bias[col];
      if (tot > bestv || (tot == bestv && col < besti)) { bestv = tot; besti = col; }
    }
    if (lane == 0) tokf[row] = (float)besti;
  }

  // phase B: soft = e * si from registers (nt: never re-read, keeps L3 for logits)
#pragma unroll
  for (int j = 0; j < 8; ++j) {
    const int i = j * 256 + tid;
    if (i < 2047) {
      f32x4 o;
      o[0] = e[j][0] * si; o[1] = e[j][1] * si;
      o[2] = e[j][2] * si; o[3] = e[j][3] * si;
      __builtin_nontemporal_store(o, S4 + i);
    }
  }
  if (extra_col >= 0) S[extra_col] = extra_e * si;
}

// ---------------- pass 3: quantized gather + commitment loss ----------------
__global__ __launch_bounds__(256) void finalize_k(const float* __restrict__ tokf,
                                                  const float* __restrict__ cb,
                                                  const float* __restrict__ xf,
                                                  float* __restrict__ q,
                                                  float* __restrict__ loss) {
  const int row  = blockIdx.x * 4 + (threadIdx.x >> 6);
  const int lane = threadIdx.x & 63;
  const int idx  = (int)tokf[row];
  const f32x4* cr = (const f32x4*)(cb + (size_t)idx * D_);
  const f32x4* xr = (const f32x4*)(xf + (size_t)row * D_);
  f32x4* qr = (f32x4*)(q + (size_t)row * D_);
  float ls = 0.f;
#pragma unroll
  for (int j = 0; j < 2; ++j) {
    const int c = lane + j * 64;
    const f32x4 cv = cr[c];
    const f32x4 xv = xr[c];
    __builtin_nontemporal_store(cv, qr + c);
    const float dx = cv[0] - xv[0], dy = cv[1] - xv[1], dz = cv[2] - xv[2], dw = cv[3] - xv[3];
    ls += dx * dx + dy * dy + dz * dz + dw * dw;
  }
#pragma unroll
  for (int o = 32; o; o >>= 1) ls += __shfl_xor(ls, o);
  if (lane == 0) atomicAdd(loss, ls * (1.0f / 4194304.0f));
}

extern "C" void kernel_launch(void* const* d_in, const int* in_sizes, int n_in,
                              void* d_out, int out_size, void* d_ws, size_t ws_size,
                              hipStream_t stream) {
  const float* x  = (const float*)d_in[0];  // inputs   [8192][512]
  const float* cb = (const float*)d_in[1];  // codebook [8192][512]
  const float* wl = (const float*)d_in[2];  // W_logits [8192][512]
  const float* bl = (const float*)d_in[3];  // b_logits [8192]
  float* out = (float*)d_out;

  float* qout   = out + OFF_Q;
  float* tokf   = out + OFF_TOK;
  float* loss   = out + OFF_LOSS;
  float* soft   = out + OFF_SOFT;
  float* logits = out + OFF_LOGITS;

  // scratch: bf16 staging at soft-region tail (rows >=7168) — read only by gemm,
  // overwritten by row_finish's soft writes which run strictly after gemm.
  unsigned short* Abf = (unsigned short*)(out + STAGE_F);
  unsigned short* Wbf = Abf + (size_t)BT_ * D_;

  hipMemsetAsync(loss, 0, 4, stream);

  to_bf16_k<<<2048, 256, 0, stream>>>((const f32x4*)x, (const f32x4*)wl,
                                      (u16x4*)Abf, (u16x4*)Wbf);
  gemm8<<<1024, 512, 0, stream>>>(Abf, Wbf, bl, logits);
  row_finish<<<8192, 256, 0, stream>>>(logits, x, wl, bl, tokf, soft);
  finalize_k<<<2048, 256, 0, stream>>>(tokf, cb, x, qout, loss);
}

// Round 15
// 321.789 us; speedup vs baseline: 1.0842x; 1.0068x over previous
//
#include <hip/hip_runtime.h>
#include <hip/hip_bf16.h>

#define BT_ 8192   // B*T
#define D_  512
#define V_  8192

// d_out float offsets (outputs concatenated in return order)
#define OFF_Q      0
#define OFF_TOK    4194304
#define OFF_LOSS   4202496
#define OFF_SOFT   4202497
#define OFF_LOGITS 71311361
// bf16 staging scratch at the TAIL of the soft region (soft rows >=7168):
// clobbered only by row_finish's soft writes, which run after all gemm reads.
#define STAGE_F    62922752

#define TAU  0.02f
#define EXP_NEG_TAU 0.98019867f   // exp(-0.02)
#define MAXC 64

typedef __attribute__((ext_vector_type(8))) short bf16x8;
typedef __attribute__((ext_vector_type(4))) float f32x4;
typedef __attribute__((ext_vector_type(4))) unsigned short u16x4;

__device__ __forceinline__ unsigned short bf16rne(float f) {
  unsigned int u = __float_as_uint(f);
  return (unsigned short)((u + 0x7fffu + ((u >> 16) & 1u)) >> 16);
}

// ---------------- pass 0: fp32 -> bf16 for X and W (block-uniform source) ----------------
// also zeroes the loss accumulator (replaces the memset dispatch)
__global__ __launch_bounds__(256) void to_bf16_k(const f32x4* __restrict__ x,
                                                 const f32x4* __restrict__ w,
                                                 u16x4* __restrict__ xa,
                                                 u16x4* __restrict__ wb,
                                                 float* __restrict__ loss) {
  if (blockIdx.x == 0 && threadIdx.x == 0) *loss = 0.f;
  const int n4 = (BT_ * D_) / 4;
  const int half = gridDim.x >> 1;
  const bool isw = blockIdx.x >= half;
  const f32x4* __restrict__ s = isw ? w : x;
  u16x4* __restrict__ d = isw ? wb : xa;
  const int b0 = isw ? blockIdx.x - half : blockIdx.x;
  for (int i = b0 * 256 + threadIdx.x; i < n4; i += half * 256) {
    const f32x4 v = s[i];
    u16x4 o;
    o[0] = bf16rne(v[0]); o[1] = bf16rne(v[1]);
    o[2] = bf16rne(v[2]); o[3] = bf16rne(v[3]);
    d[i] = o;
  }
}

// ---------------- pass 1: 256x256 2-phase bf16 MFMA GEMM (pure-store epilogue) ----------------
__device__ __forceinline__ void gload_lds16(const void* g, void* l) {
  __builtin_amdgcn_global_load_lds((const __attribute__((address_space(1))) void*)g,
                                   (__attribute__((address_space(3))) void*)l,
                                   16, 0, 0);
}

__device__ __forceinline__ void barf() {
  __builtin_amdgcn_s_barrier();
  asm volatile("" ::: "memory");
}
__device__ __forceinline__ void vmcnt0() { asm volatile("s_waitcnt vmcnt(0)" ::: "memory"); }
__device__ __forceinline__ void vmcnt2() { asm volatile("s_waitcnt vmcnt(2)" ::: "memory"); }
__device__ __forceinline__ void vmcnt4() { asm volatile("s_waitcnt vmcnt(4)" ::: "memory"); }

// stage one CONTIGUOUS half-tile (16 KB) of K-tile `ktile` (used for B).
// LDS dest linear, global source inverse-swizzled (T2 both-sides):
// addr ^= ((row&7)<<4).
__device__ __forceinline__ void stage_unit(const char* __restrict__ tb, char* ldsRegion,
                                           int ktile, int half, int wid, int lane) {
#pragma unroll
  for (int issue = 0; issue < 2; ++issue) {
    const int d = half * 16384 + issue * 8192 + wid * 1024 + lane * 16;
    const int l = d ^ (((d >> 7) & 7) << 4);
    gload_lds16(tb + (size_t)(l >> 7) * 1024 + ktile * 128 + (l & 127),
                ldsRegion + half * 16384 + issue * 8192 + wid * 1024);
  }
}

// stage one INTERLEAVED A unit u: rows {64u..64u+63} U {128+64u..191+64u}.
// unit0 = ph1's A01 rows (wr*128 + 0..63 for both wr), unit1 = ph2's A23 rows.
__device__ __forceinline__ void stage_unitA(const char* __restrict__ tb, char* ldsRegion,
                                            int ktile, int u, int wid, int lane) {
#pragma unroll
  for (int issue = 0; issue < 2; ++issue) {
    const int rowbase = issue * 128 + u * 64;
    const int dd = rowbase * 128 + wid * 1024 + lane * 16;
    const int l = dd ^ (((dd >> 7) & 7) << 4);
    gload_lds16(tb + (size_t)(l >> 7) * 1024 + ktile * 128 + (l & 127),
                ldsRegion + rowbase * 128 + wid * 1024);
  }
}

__device__ __forceinline__ bf16x8 rdfrag(const char* base, int R, int ks, int g) {
  return *(const bf16x8*)(base + R * 128 + ((ks * 64 + 16 * g) ^ ((R & 7) << 4)));
}

// 2-phase K-tile — RETIRE-BEFORE-BARRIER discipline (r14 fix):
// vmcnt guarantees are per-wave; only a vmcnt executed BEFORE an s_barrier
// publishes "my slices landed" to other waves. Every rdfrag below is covered
// by a {vmcnt, barrier} pair upstream:
//   entry(t):  prior ph2's vmcnt2+barf retired A_u0(t),B0(t),B1(t) (all waves).
//   ph1(t):    read A_u0(t)+B0123(t); stage B0(t+1),B1(t+1); barf; MFMA;
//              vmcnt4 -> retires A_u1(t) (leaves B(t+1)=4); barf.   [publishes A_u1(t)]
//   ph2(t):    read A_u1(t); stage A_u0(t+1),A_u1(t+1); barf; MFMA;
//              vmcnt2 -> leaves only A_u1(t+1); barf.               [publishes B,A_u0(t+1)]
// The sole cross-barrier in-flight unit A_u1(t+1) lands in rows {64-127,192-255},
// disjoint from ph1(t+1)'s reads {0-63,128-191}.
__device__ __forceinline__ void kgroup(int t, int smode, char* lds,
                                       const char* __restrict__ Ab,
                                       const char* __restrict__ Bb,
                                       int wr, int wc, int lane, int wid,
                                       f32x4 (&acc)[8][4]) {
  char* aL = lds + (t & 1) * 32768;
  char* bL = lds + 65536 + (t & 1) * 32768;
  char* aS = lds + ((t & 1) ^ 1) * 32768;
  char* bS = lds + 65536 + ((t & 1) ^ 1) * 32768;
  const int cg = lane & 15, g = lane >> 4;
  bf16x8 a[4][2], b[4][2];

  // ---- phase 1: read A01(t) [unit0] + B0123(t); stage (t+1).B0,(t+1).B1
#pragma unroll
  for (int m = 0; m < 4; ++m)
#pragma unroll
    for (int ks = 0; ks < 2; ++ks)
      a[m][ks] = rdfrag(aL, wr * 128 + m * 16 + cg, ks, g);
#pragma unroll
  for (int n = 0; n < 4; ++n)
#pragma unroll
    for (int ks = 0; ks < 2; ++ks)
      b[n][ks] = rdfrag(bL, wc * 64 + n * 16 + cg, ks, g);
  if (smode >= 1) {
    stage_unit(Bb, bS, t + 1, 0, wid, lane);
    stage_unit(Bb, bS, t + 1, 1, wid, lane);
  }
  barf();
  __builtin_amdgcn_s_setprio(1);
#pragma unroll
  for (int m = 0; m < 4; ++m)
#pragma unroll
    for (int n = 0; n < 4; ++n)
#pragma unroll
      for (int ks = 0; ks < 2; ++ks)
        acc[m][n] = __builtin_amdgcn_mfma_f32_16x16x32_bf16(a[m][ks], b[n][ks], acc[m][n], 0, 0, 0);
  __builtin_amdgcn_s_setprio(0);
  if (smode >= 1) vmcnt4(); else vmcnt0();   // retire A_u1(t) BEFORE the barrier
  barf();                                    // -> publishes it to all waves

  // ---- phase 2: read A23(t) [unit1, now published]; stage (t+1).A units
#pragma unroll
  for (int m = 0; m < 4; ++m)
#pragma unroll
    for (int ks = 0; ks < 2; ++ks)
      a[m][ks] = rdfrag(aL, wr * 128 + (m + 4) * 16 + cg, ks, g);
  if (smode >= 1) {
    stage_unitA(Ab, aS, t + 1, 0, wid, lane);
    stage_unitA(Ab, aS, t + 1, 1, wid, lane);   // A_u1(t+1) last -> the in-flight item
  }
  barf();
  __builtin_amdgcn_s_setprio(1);
#pragma unroll
  for (int m = 0; m < 4; ++m)
#pragma unroll
    for (int n = 0; n < 4; ++n)
#pragma unroll
      for (int ks = 0; ks < 2; ++ks)
        acc[m + 4][n] = __builtin_amdgcn_mfma_f32_16x16x32_bf16(a[m][ks], b[n][ks], acc[m + 4][n], 0, 0, 0);
  __builtin_amdgcn_s_setprio(0);
  if (smode >= 1) vmcnt2();   // retire B(t+1),A_u0(t+1) BEFORE barrier; leave A_u1(t+1)
  barf();
}

__global__ __launch_bounds__(512) void gemm8(const unsigned short* __restrict__ A,
                                             const unsigned short* __restrict__ B,
                                             const float* __restrict__ bias,
                                             float* __restrict__ C) {
  __shared__ char lds[131072];  // A dbuf 64K | B dbuf 64K ; reused as C retile
  const int tid  = threadIdx.x;
  const int lane = tid & 63;
  const int wid  = tid >> 6;           // 8 waves: 2M x 4N
  const int wr   = wid >> 2, wc = wid & 3;

  // bijective XCD chunking over the 32x32 block grid (8x16 blocks per XCD)
  const int bid = blockIdx.x;
  const int xcd = bid & 7;
  const int s   = bid >> 3;
  const int by  = (xcd >> 1) * 8 + (s >> 4);
  const int bx  = (xcd & 1) * 16 + (s & 15);
  const int row0 = by * 256, col0 = bx * 256;

  const char* Ab = (const char*)A + (size_t)row0 * (D_ * 2);
  const char* Bb = (const char*)B + (size_t)col0 * (D_ * 2);

  f32x4 acc[8][4] = {};

  // prologue: stage tile0; A_u1(0) issued LAST (the in-flight item after vmcnt(2))
  stage_unit(Bb, lds + 65536, 0, 0, wid, lane);
  stage_unit(Bb, lds + 65536, 0, 1, wid, lane);
  stage_unitA(Ab, lds, 0, 0, wid, lane);
  stage_unitA(Ab, lds, 0, 1, wid, lane);
  vmcnt2();   // retire B(0), A_u0(0) before barrier -> published for ph1(0)
  barf();

  for (int t = 0; t < 7; ++t)
    kgroup(t, 1, lds, Ab, Bb, wr, wc, lane, wid, acc);
  kgroup(7, 0, lds, Ab, Bb, wr, wc, lane, wid, acc);

  // ---- epilogue: PURE retile + coalesced 1KB row stores ----
  // LDS rows rotated by -3 cols so the (base%4==1) global misalignment maps to
  // aligned LDS f32x4 reads: lds word (c+253)&255 holds col c.
  const int cg = lane & 15, g = lane >> 4;
  float bv[4];
#pragma unroll
  for (int n = 0; n < 4; ++n) bv[n] = bias[col0 + wc * 64 + n * 16 + cg];

  float* cl = (float*)lds;
  __syncthreads();
#pragma unroll
  for (int h = 0; h < 2; ++h) {
    if (wr == h) {
#pragma unroll
      for (int m = 0; m < 8; ++m)
#pragma unroll
        for (int n = 0; n < 4; ++n) {
          const int cw = ((wc * 64 + n * 16 + cg) + 253) & 255;
#pragma unroll
          for (int rr = 0; rr < 4; ++rr) {
            const int R = m * 16 + 4 * g + rr;
            cl[R * 256 + cw] = acc[m][n][rr] + bv[n];
          }
        }
    }
    __syncthreads();
#pragma unroll
    for (int k = 0; k < 16; ++k) {
      const int r = wid * 16 + k;
      const f32x4 v = *(const f32x4*)((char*)cl + r * 1024 + lane * 16);
      const int grow = row0 + h * 128 + r;
      float* Crow = C + (size_t)grow * V_ + col0;
      if (lane < 63) {
        *((f32x4*)(Crow + 3) + lane) = v;   // plain: row_finish re-reads soon
      } else {
        Crow[255] = v[0]; Crow[0] = v[1]; Crow[1] = v[2]; Crow[2] = v[3];
      }
    }
    __syncthreads();
  }
}

// ---- pass 2: single-pass row softmax + exact-fp32 argmax rescue (register-resident) ----
// Row mapping = write-recency LIFO: gemm generation g wrote panels with
// (by&7) in {2g, 2g+1}; we read gen 3 first (still L3-resident), then 2,1,0.
__global__ __launch_bounds__(256) void row_finish(const float* __restrict__ logits,
                                                  const float* __restrict__ xf,
                                                  const float* __restrict__ wf,
                                                  const float* __restrict__ bias,
                                                  float* __restrict__ tokf,
                                                  float* __restrict__ soft) {
  const int b    = blockIdx.x;
  const int gen  = 3 - (b >> 11);          // newest generation first
  const int idx  = b & 2047;
  const int p    = idx >> 8;               // 0..7 panel within generation
  const int by   = (p >> 1) * 8 + gen * 2 + (p & 1);
  const int row  = by * 256 + (idx & 255);
  const int tid  = threadIdx.x;
  const int lane = tid & 63;
  const int wv   = tid >> 6;

  __shared__ float redM[4], redS[4];
  __shared__ int   cnum;
  __shared__ int   cidx[MAXC];

  const float* L = logits + (size_t)row * V_;
  float*       S = soft   + (size_t)row * V_;
  const f32x4* L4 = (const f32x4*)(L + 3);  // 16B-aligned; valid i in [0,2047)
  f32x4*       S4 = (f32x4*)(S + 3);

  // phase A: load + exp (once), per-thread max/sum
  f32x4 e[8];
  float m_e = 0.f, s = 0.f;   // all e > 0
#pragma unroll
  for (int j = 0; j < 8; ++j) {
    const int i = j * 256 + tid;
    if (i < 2047) {
      const f32x4 v = L4[i];
      f32x4 t;
      t[0] = __expf(v[0]); t[1] = __expf(v[1]);
      t[2] = __expf(v[2]); t[3] = __expf(v[3]);
      e[j] = t;
      m_e = fmaxf(m_e, fmaxf(fmaxf(t[0], t[1]), fmaxf(t[2], t[3])));
      s += t[0] + t[1] + t[2] + t[3];
    } else {
      e[j][0] = 0.f; e[j][1] = 0.f; e[j][2] = 0.f; e[j][3] = 0.f;
    }
  }
  // head (cols 0..2) + tail (col 8191) extras on threads 0..3
  float extra_e = 0.f;
  int   extra_col = -1;
  if (tid < 3)       extra_col = tid;
  else if (tid == 3) extra_col = 8191;
  if (extra_col >= 0) {
    extra_e = __expf(L[extra_col]);
    m_e = fmaxf(m_e, extra_e);
    s += extra_e;
  }
  // block reduce
#pragma unroll
  for (int o = 1; o < 64; o <<= 1) {
    m_e = fmaxf(m_e, __shfl_xor(m_e, o));
    s += __shfl_xor(s, o);
  }
  if (lane == 0) { redM[wv] = m_e; redS[wv] = s; }
  if (tid == 0) cnum = 0;
  __syncthreads();
  m_e = fmaxf(fmaxf(redM[0], redM[1]), fmaxf(redM[2], redM[3]));
  s   = redS[0] + redS[1] + redS[2] + redS[3];
  const float si    = 1.0f / s;
  const float thr_e = m_e * EXP_NEG_TAU;   // e >= thr_e  <=>  logit >= max - TAU

  // candidate collection (monotonic in e)
#pragma unroll
  for (int j = 0; j < 8; ++j) {
    const int i = j * 256 + tid;
#pragma unroll
    for (int q = 0; q < 4; ++q)
      if (e[j][q] >= thr_e) {
        const int pp = atomicAdd(&cnum, 1);
        if (pp < MAXC) cidx[pp] = 3 + 4 * i + q;
      }
  }
  if (extra_col >= 0 && extra_e >= thr_e) {
    const int pp = atomicAdd(&cnum, 1);
    if (pp < MAXC) cidx[pp] = extra_col;
  }
  __syncthreads();

  // wave 0: exact-fp32 rescue over candidates; waves 1-3 go straight to stores
  if (wv == 0) {
    const int cnt = min(cnum, MAXC);
    float bestv = -1e30f;
    int   besti = 0x7fffffff;
    const float4* xr4 = (const float4*)(xf + (size_t)row * D_);
    for (int c = 0; c < cnt; ++c) {
      const int col = cidx[c];
      const float4* wr4 = (const float4*)(wf + (size_t)col * D_);
      float pr = 0.f;
#pragma unroll
      for (int q = 0; q < 2; ++q) {
        const float4 av = xr4[lane + 64 * q];
        const float4 bvv = wr4[lane + 64 * q];
        pr += av.x * bvv.x + av.y * bvv.y + av.z * bvv.z + av.w * bvv.w;
      }
#pragma unroll
      for (int o = 1; o < 64; o <<= 1) pr += __shfl_xor(pr, o);
      const float tot = pr + bias[col];
      if (tot > bestv || (tot == bestv && col < besti)) { bestv = tot; besti = col; }
    }
    if (lane == 0) tokf[row] = (float)besti;
  }

  // phase B: soft = e * si from registers (nt: never re-read, keeps L3 for logits)
#pragma unroll
  for (int j = 0; j < 8; ++j) {
    const int i = j * 256 + tid;
    if (i < 2047) {
      f32x4 o;
      o[0] = e[j][0] * si; o[1] = e[j][1] * si;
      o[2] = e[j][2] * si; o[3] = e[j][3] * si;
      __builtin_nontemporal_store(o, S4 + i);
    }
  }
  if (extra_col >= 0) S[extra_col] = extra_e * si;
}

// ---------------- pass 3: quantized gather + commitment loss ----------------
__global__ __launch_bounds__(256) void finalize_k(const float* __restrict__ tokf,
                                                  const float* __restrict__ cb,
                                                  const float* __restrict__ xf,
                                                  float* __restrict__ q,
                                                  float* __restrict__ loss) {
  const int row  = blockIdx.x * 4 + (threadIdx.x >> 6);
  const int lane = threadIdx.x & 63;
  const int idx  = (int)tokf[row];
  const f32x4* cr = (const f32x4*)(cb + (size_t)idx * D_);
  const f32x4* xr = (const f32x4*)(xf + (size_t)row * D_);
  f32x4* qr = (f32x4*)(q + (size_t)row * D_);
  float ls = 0.f;
#pragma unroll
  for (int j = 0; j < 2; ++j) {
    const int c = lane + j * 64;
    const f32x4 cv = cr[c];
    const f32x4 xv = xr[c];
    __builtin_nontemporal_store(cv, qr + c);
    const float dx = cv[0] - xv[0], dy = cv[1] - xv[1], dz = cv[2] - xv[2], dw = cv[3] - xv[3];
    ls += dx * dx + dy * dy + dz * dz + dw * dw;
  }
#pragma unroll
  for (int o = 32; o; o >>= 1) ls += __shfl_xor(ls, o);
  if (lane == 0) atomicAdd(loss, ls * (1.0f / 4194304.0f));
}

extern "C" void kernel_launch(void* const* d_in, const int* in_sizes, int n_in,
                              void* d_out, int out_size, void* d_ws, size_t ws_size,
                              hipStream_t stream) {
  const float* x  = (const float*)d_in[0];  // inputs   [8192][512]
  const float* cb = (const float*)d_in[1];  // codebook [8192][512]
  const float* wl = (const float*)d_in[2];  // W_logits [8192][512]
  const float* bl = (const float*)d_in[3];  // b_logits [8192]
  float* out = (float*)d_out;

  float* qout   = out + OFF_Q;
  float* tokf   = out + OFF_TOK;
  float* loss   = out + OFF_LOSS;
  float* soft   = out + OFF_SOFT;
  float* logits = out + OFF_LOGITS;

  // scratch: bf16 staging at soft-region tail (rows >=7168) — read only by gemm,
  // overwritten by row_finish's soft writes which run strictly after gemm.
  unsigned short* Abf = (unsigned short*)(out + STAGE_F);
  unsigned short* Wbf = Abf + (size_t)BT_ * D_;

  to_bf16_k<<<2048, 256, 0, stream>>>((const f32x4*)x, (const f32x4*)wl,
                                      (u16x4*)Abf, (u16x4*)Wbf, loss);
  gemm8<<<1024, 512, 0, stream>>>(Abf, Wbf, bl, logits);
  row_finish<<<8192, 256, 0, stream>>>(logits, x, wl, bl, tokf, soft);
  finalize_k<<<2048, 256, 0, stream>>>(tokf, cb, x, qout, loss);
}